// Round 13
// baseline (90.047 us; speedup 1.0000x reference)
//
#include <hip/hip_runtime.h>

#define NB 32
#define TT 512
#define UU 100
#define UM 101   // U+1
#define VV 4096
#define NEG (-1e30f)
#define WIN 64
#define L2E 1.4426950408889634f
#define LN2 0.6931471805599453f

__device__ __forceinline__ float vexp2(float x){ float r; asm("v_exp_f32 %0, %1" : "=v"(r) : "v"(x)); return r; }
__device__ __forceinline__ float vlog2(float x){ float r; asm("v_log_f32 %0, %1" : "=v"(r) : "v"(x)); return r; }

// logaddexp in log2 domain
__device__ __forceinline__ float lae2(float a, float b) {
    float m  = fmaxf(a, b);
    float nd = fminf(a, b) - m;          // = -|a-b|
    return m + vlog2(1.0f + vexp2(nd));
}

// k1: STREAMING gather. Block (tt, n) covers enc rows t = tt*32 .. +31 (t < tin).
// Each row is read row-linearly with coalesced float4 loads (sequential-access
// rate ~6-7 TB/s vs the measured ~1 TB/s random-line wall), staged to LDS, and
// 100 threads select rowL[y_j]. 1-row software pipeline: load regs row r+1
// while selecting row r. Outputs: em[n][j][t] (t-contiguous, *L2E) and
// blk[n][t] = enc[n][t][0]*L2E.
__global__ __launch_bounds__(256) void gather_k(
        const float* __restrict__ enc, const int* __restrict__ tgt,
        const int* __restrict__ ilen,
        float* __restrict__ em, float* __restrict__ blk) {
    int tt = blockIdx.x, n = blockIdx.y;
    int tin = ilen[n];
    int t0 = tt * 32;
    if (t0 >= tin) return;
    int rows = min(32, tin - t0);

    __shared__ float rowL[VV];           // one enc row, 16 KB
    __shared__ float tile[32][105];      // [t_local][j], pitch 105 (conflict-free)
    __shared__ float blkT[32];
    __shared__ int   yL[UU];

    int tid = threadIdx.x;
    if (tid < UU) yL[tid] = tgt[n * UU + tid];
    const float* encn = enc + (size_t)n * TT * VV;

    float4 vA0, vA1, vA2, vA3, vB0, vB1, vB2, vB3;
    {   // prologue: load row t0
        const float4* rp = (const float4*)(encn + (size_t)t0 * VV);
        vA0 = rp[tid]; vA1 = rp[tid + 256]; vA2 = rp[tid + 512]; vA3 = rp[tid + 768];
    }
    __syncthreads();                     // yL ready

    float4* rl = (float4*)rowL;
    for (int r = 0; r < rows; r += 2) {
        // ---- even row r (data in vA) ----
        rl[tid] = vA0; rl[tid + 256] = vA1; rl[tid + 512] = vA2; rl[tid + 768] = vA3;
        if (r + 1 < rows) {              // issue loads for row r+1 (hide under select)
            const float4* rp = (const float4*)(encn + (size_t)(t0 + r + 1) * VV);
            vB0 = rp[tid]; vB1 = rp[tid + 256]; vB2 = rp[tid + 512]; vB3 = rp[tid + 768];
        }
        __syncthreads();
        if (tid < UU)  tile[r][tid] = rowL[yL[tid]] * L2E;
        if (tid == UU) blkT[r] = rowL[0] * L2E;
        __syncthreads();
        // ---- odd row r+1 (data in vB) ----
        if (r + 1 < rows) {
            rl[tid] = vB0; rl[tid + 256] = vB1; rl[tid + 512] = vB2; rl[tid + 768] = vB3;
            if (r + 2 < rows) {
                const float4* rp = (const float4*)(encn + (size_t)(t0 + r + 2) * VV);
                vA0 = rp[tid]; vA1 = rp[tid + 256]; vA2 = rp[tid + 512]; vA3 = rp[tid + 768];
            }
            __syncthreads();
            if (tid < UU)  tile[r + 1][tid] = rowL[yL[tid]] * L2E;
            if (tid == UU) blkT[r + 1] = rowL[0] * L2E;
            __syncthreads();
        }
    }

    // coalesced stores: em[n][j][t0 + tl]
    for (int idx = tid; idx < UU * 32; idx += 256) {
        int j = idx >> 5, tl = idx & 31;
        if (tl < rows)
            em[((size_t)n * UU + j) * TT + t0 + tl] = tile[tl][j];
    }
    if (tid < rows) blk[n * TT + t0 + tid] = blkT[tid];
}

// k2: fused DP (R12-proven consumer, verbatim math). Wave 0 consumes
// 64-diagonal LDS windows; waves 1..15 stage the next window from em with
// coalesced reads. Lane L owns u=2L (a0) and u=2L+1 (a1).
__global__ __launch_bounds__(1024, 1) void dp_k(
        const float* __restrict__ blk, const float* __restrict__ dec,
        const int* __restrict__ tgt, const int* __restrict__ ilen,
        const int* __restrict__ tlen, const float* __restrict__ em,
        float* __restrict__ out) {
    __shared__ float emL[2][WIN][130];   // [buf][dm][u], padded (+2)
    __shared__ float blkL[864];          // blkL[128+t] = blk[n][t], NEG pads
    __shared__ float dvxL[UU];           // dec[n][j][y_j]*L2E

    int n = blockIdx.x, tid = threadIdx.x;
    int tin = ilen[n], tg = tlen[n];
    int dend = tin - 1 + tg;
    int E = (dend + WIN - 1) / WIN;
    const float* decn = dec + (size_t)n * UM * VV;

    for (int i = tid; i < 864; i += 1024)
        blkL[i] = (i >= 128 && i < 128 + TT) ? blk[n * TT + (i - 128)] : NEG;
    if (tid < UU) {
        int y = tgt[n * UU + tid];
        dvxL[tid] = decn[(size_t)tid * VV + y] * L2E;
    }
    __syncthreads();

    int wave = tid >> 6, lane = tid & 63;
    const float* emn = em + (size_t)n * UU * TT;

    // producers: stage window w (diagonals base+1 .. base+64).
    // row r: 0..99 -> data column u=r+1; r=100 -> u=0 (NEG); r=101..127 -> u=r (NEG).
    auto FILLWIN = [&](int w, int base) {
        for (int r = wave - 1; r < 128; r += 15) {
            int u = (r < 100) ? (r + 1) : ((r == 100) ? 0 : r);
            int t = base + 1 + lane - u;          // dm = lane
            float val = NEG;
            if (r < 100 && r < tg && t >= 0 && t < tin)
                val = emn[(size_t)r * TT + t] + dvxL[r];
            emL[w][lane][u] = val;
        }
    };

    if (wave != 0) FILLWIN(0, 0);        // prefill window 0

    // consumer state
    bool fx16 = (lane == 16), fx32 = (lane == 32), fx48 = (lane == 48);
    bool cap0 = (2 * lane == tg), cap1 = (2 * lane + 1 == tg);
    float bd0 = decn[(size_t)min(2 * lane, UM - 1) * VV] * L2E;
    float bd1 = decn[(size_t)min(2 * lane + 1, UM - 1) * VV] * L2E;
    int ib0 = 127 - 2 * lane;            // blkL idx of slot0's blk[t-1] is ib0 + d
    float a0 = (lane == 0) ? 0.0f : NEG; // alpha[0][0] = 0 at d=0
    float a1 = NEG;
    float res = NEG;

    float Re0[8], Re1[8], Rb0[8], Rb1[8], Se0[8], Se1[8], Sb0[8], Sb1[8];

    auto REFILL = [&](float (&e0)[8], float (&e1)[8], float (&b0)[8], float (&b1)[8],
                      const float* emb, int j0, int base) {
#pragma unroll
        for (int k = 0; k < 8; ++k) {
            int dm = j0 + k, d = base + 1 + dm;
            float2 ev = *(const float2*)(emb + dm * 130 + 2 * lane);
            e0[k] = ev.x; e1[k] = ev.y;
            b0[k] = blkL[ib0 + d] + bd0;
            b1[k] = blkL[ib0 + d - 1] + bd1;
        }
        __builtin_amdgcn_sched_barrier(0);
    };

    auto STEPS = [&](float (&e0)[8], float (&e1)[8], float (&b0)[8], float (&b1)[8],
                     int j0, int base) {
#pragma unroll
        for (int k = 0; k < 8; ++k) {
            int dd = base + 1 + j0 + k;
            // left neighbor of u=2L is lane L-1's a1: DPP row_shr:1 + seam fixups
            int sh = __builtin_amdgcn_update_dpp(__float_as_int(NEG), __float_as_int(a1),
                                                 0x111, 0xF, 0xF, false);   // row_shr:1
            float s15 = __int_as_float(__builtin_amdgcn_readlane(__float_as_int(a1), 15));
            float s31 = __int_as_float(__builtin_amdgcn_readlane(__float_as_int(a1), 31));
            float s47 = __int_as_float(__builtin_amdgcn_readlane(__float_as_int(a1), 47));
            float l0 = __int_as_float(sh);
            l0 = fx16 ? s15 : l0;
            l0 = fx32 ? s31 : l0;
            l0 = fx48 ? s47 : l0;
            float bt0 = a0 + b0[k], et0 = l0 + e0[k];
            float bt1 = a1 + b1[k], et1 = a0 + e1[k];   // old a0: same-lane left neighbor
            a0 = lae2(bt0, et0);
            a1 = lae2(bt1, et1);
            if (dd == dend) { if (cap0) res = a0; if (cap1) res = a1; }
        }
        __builtin_amdgcn_sched_barrier(0);
    };

    __syncthreads();                     // window 0 ready

    for (int e = 0; e < E; ++e) {
        if (wave == 0) {
            int base = e * WIN;
            const float* emb = &emL[e & 1][0][0];
            REFILL(Re0, Re1, Rb0, Rb1, emb, 0, base);
            REFILL(Se0, Se1, Sb0, Sb1, emb, 8, base);  STEPS(Re0, Re1, Rb0, Rb1, 0, base);
            REFILL(Re0, Re1, Rb0, Rb1, emb, 16, base); STEPS(Se0, Se1, Sb0, Sb1, 8, base);
            REFILL(Se0, Se1, Sb0, Sb1, emb, 24, base); STEPS(Re0, Re1, Rb0, Rb1, 16, base);
            REFILL(Re0, Re1, Rb0, Rb1, emb, 32, base); STEPS(Se0, Se1, Sb0, Sb1, 24, base);
            REFILL(Se0, Se1, Sb0, Sb1, emb, 40, base); STEPS(Re0, Re1, Rb0, Rb1, 32, base);
            REFILL(Re0, Re1, Rb0, Rb1, emb, 48, base); STEPS(Se0, Se1, Sb0, Sb1, 40, base);
            REFILL(Se0, Se1, Sb0, Sb1, emb, 56, base); STEPS(Re0, Re1, Rb0, Rb1, 48, base);
            STEPS(Se0, Se1, Sb0, Sb1, 56, base);
        } else if (e + 1 < E) {
            FILLWIN((e + 1) & 1, (e + 1) * WIN);
        }
        __syncthreads();
    }

    if (wave == 0 && (cap0 | cap1)) {
        float fin  = blkL[128 + tin - 1];
        float bdtg = decn[(size_t)tg * VV] * L2E;
        out[n] = (res + fin + bdtg) * LN2;
    }
}

extern "C" void kernel_launch(void* const* d_in, const int* in_sizes, int n_in,
                              void* d_out, int out_size, void* d_ws, size_t ws_size,
                              hipStream_t hs) {
    const float* enc  = (const float*)d_in[0];
    const float* dec  = (const float*)d_in[1];
    const int*   tgt  = (const int*)d_in[2];
    const int*   ilen = (const int*)d_in[3];
    const int*   tlen = (const int*)d_in[4];
    float* out = (float*)d_out;

    float* em  = (float*)d_ws;                        // NB*UU*TT floats = 6.55 MB
    float* blk = em + (size_t)NB * UU * TT;           // NB*TT floats = 64 KB

    hipLaunchKernelGGL(gather_k, dim3(16, NB), dim3(256), 0, hs,
                       enc, tgt, ilen, em, blk);
    hipLaunchKernelGGL(dp_k, dim3(NB), dim3(1024), 0, hs,
                       blk, dec, tgt, ilen, tlen, em, out);
}

// Round 14
// 71.812 us; speedup vs baseline: 1.2539x; 1.2539x over previous
//
#include <hip/hip_runtime.h>

#define NB 32
#define TT 512
#define UU 100
#define UM 101   // U+1
#define VV 4096
#define NEG (-1e30f)
#define WIN 32           // diagonals per window
#define RING 4           // ring depth (windows in flight)
#define PITCH 104        // u-pitch of a window row (u = 0..103 stored)
#define EMSLOT (WIN * PITCH + 24)   // +24: consumer float2 reads reach u=127
#define L2E 1.4426950408889634f
#define LN2 0.6931471805599453f

__device__ __forceinline__ float vexp2(float x){ float r; asm("v_exp_f32 %0, %1" : "=v"(r) : "v"(x)); return r; }
__device__ __forceinline__ float vlog2(float x){ float r; asm("v_log_f32 %0, %1" : "=v"(r) : "v"(x)); return r; }

// logaddexp in log2 domain
__device__ __forceinline__ float lae2(float a, float b) {
    float m  = fmaxf(a, b);
    float nd = fminf(a, b) - m;          // = -|a-b|
    return m + vlog2(1.0f + vexp2(nd));
}

// One block per n (1024 threads). Wave 0 = DP consumer; waves 1..15 = producers.
// Decoupled via a 4-deep LDS window ring with LDS-atomic flags: producers
// free-run up to RING windows ahead (no __syncthreads in the main loop), so
// producer-stall and consumer-idle no longer add up.
__global__ __launch_bounds__(1024, 1) void fused_k(
        const float* __restrict__ enc, const float* __restrict__ dec,
        const int* __restrict__ tgt, const int* __restrict__ ilen,
        const int* __restrict__ tlen, float* __restrict__ out) {
    __shared__ float emL[RING][EMSLOT];  // emit edges, window ring (53.6 KB)
    __shared__ float blkL[864];          // blkL[128+t] = enc[n][t][0]*L2E, NEG pads
    __shared__ float dvxL[UU];           // dec[n][j][y_j]*L2E
    __shared__ int   tgtL[UU];
    __shared__ int   fin[RING];          // producer-waves-done count per slot
    __shared__ int   cons;               // windows fully consumed

    int n = blockIdx.x, tid = threadIdx.x;
    int tin = ilen[n], tg = tlen[n];
    int dend = tin - 1 + tg;
    int E = (dend + WIN - 1) / WIN;      // windows cover d = 1 .. E*32 >= dend
    const float* encn = enc + (size_t)n * TT * VV;
    const float* decn = dec + (size_t)n * UM * VV;

    for (int i = tid; i < 864; i += 1024)
        blkL[i] = (i >= 128 && i < 128 + TT) ? encn[(size_t)(i - 128) * VV] * L2E : NEG;
    if (tid < UU) {
        int y = tgt[n * UU + tid];
        tgtL[tid] = y;
        dvxL[tid] = decn[(size_t)tid * VV + y] * L2E;
    }
    if (tid < RING) fin[tid] = 0;
    if (tid == RING) cons = 0;
    __syncthreads();                     // the only block-wide barrier

    int wave = tid >> 6, lane = tid & 63;

    if (wave != 0) {
        // ---------------- producers (15 waves) ----------------
        int cbase = (wave - 1) * 64 + lane;       // 0..959
        for (int w = 0; w < E; ++w) {
            int s = w & (RING - 1);
            // wait until slot s is free (consumer has finished window w-RING)
            while (*(volatile int*)&cons + RING <= w) __builtin_amdgcn_s_sleep(2);
            float ev[4]; bool ok[4]; int dmA[4], uA[4];
            // phase 1: issue all valid gather loads (4 in flight per lane)
#pragma unroll
            for (int it = 0; it < 4; ++it) {
                int c = cbase + it * 960;          // cell index in window
                int dm = (unsigned)c / PITCH;      // magic-mul div
                int u  = c - dm * PITCH;
                int d  = w * WIN + 1 + dm;
                int t  = d - u;
                bool v = (c < WIN * PITCH) & (u >= 1) & (u <= tg) & (t >= 0) & (t < tin);
                dmA[it] = dm; uA[it] = u; ok[it] = v;
                ev[it] = NEG;
                if (v) ev[it] = encn[(size_t)t * VV + tgtL[u - 1]];   // exec-masked
            }
            // phase 2: select + LDS store
#pragma unroll
            for (int it = 0; it < 4; ++it) {
                int c = cbase + it * 960;
                if (c < WIN * PITCH) {
                    float e = ok[it] ? fmaf(ev[it], L2E, dvxL[uA[it] - 1]) : NEG;
                    emL[s][dmA[it] * PITCH + uA[it]] = e;
                }
            }
            __threadfence_block();               // LDS writes visible before flag
            if (lane == 0) atomicAdd(&fin[s], 1);
        }
        return;
    }

    // ---------------- consumer (wave 0) ----------------
    // lane L owns u=2L (a0) and u=2L+1 (a1); proven R12 math.
    float bd0 = decn[(size_t)min(2 * lane, UM - 1) * VV] * L2E;
    float bd1 = decn[(size_t)min(2 * lane + 1, UM - 1) * VV] * L2E;
    int ib0 = 127 - 2 * lane;            // blkL idx of slot0's blk[t-1] is ib0 + d
    bool cap0 = (2 * lane == tg), cap1 = (2 * lane + 1 == tg);
    bool fx16 = (lane == 16), fx32 = (lane == 32), fx48 = (lane == 48);
    float a0 = (lane == 0) ? 0.0f : NEG; // alpha[0][0] = 0 at d=0
    float a1 = NEG;
    float res = NEG;

    float Ae0[8], Ae1[8], Ab0[8], Ab1[8], Be0[8], Be1[8], Bb0[8], Bb1[8];

    auto REFILL = [&](float (&e0)[8], float (&e1)[8], float (&b0)[8], float (&b1)[8],
                      const float* emb, int j0, int base) {
#pragma unroll
        for (int k = 0; k < 8; ++k) {
            int dm = j0 + k, d = base + 1 + dm;
            float2 ev = *(const float2*)(emb + dm * PITCH + 2 * lane);
            e0[k] = ev.x; e1[k] = ev.y;          // u >= 104 lanes read pad junk (never used)
            b0[k] = blkL[ib0 + d] + bd0;
            b1[k] = blkL[ib0 + d - 1] + bd1;
        }
        __builtin_amdgcn_sched_barrier(0);
    };

    auto STEPS = [&](float (&e0)[8], float (&e1)[8], float (&b0)[8], float (&b1)[8],
                     int j0, int base) {
#pragma unroll
        for (int k = 0; k < 8; ++k) {
            int dd = base + 1 + j0 + k;
            // left neighbor of u=2L is lane L-1's a1: DPP row_shr:1 + seam fixups
            int sh = __builtin_amdgcn_update_dpp(__float_as_int(NEG), __float_as_int(a1),
                                                 0x111, 0xF, 0xF, false);   // row_shr:1
            float s15 = __int_as_float(__builtin_amdgcn_readlane(__float_as_int(a1), 15));
            float s31 = __int_as_float(__builtin_amdgcn_readlane(__float_as_int(a1), 31));
            float s47 = __int_as_float(__builtin_amdgcn_readlane(__float_as_int(a1), 47));
            float l0 = __int_as_float(sh);
            l0 = fx16 ? s15 : l0;
            l0 = fx32 ? s31 : l0;
            l0 = fx48 ? s47 : l0;
            float bt0 = a0 + b0[k], et0 = l0 + e0[k];
            float bt1 = a1 + b1[k], et1 = a0 + e1[k];   // old a0: same-lane left neighbor
            a0 = lae2(bt0, et0);
            a1 = lae2(bt1, et1);
            if (dd == dend) { if (cap0) res = a0; if (cap1) res = a1; }
        }
        __builtin_amdgcn_sched_barrier(0);
    };

    for (int w = 0; w < E; ++w) {
        int s = w & (RING - 1);
        while (*(volatile int*)&fin[s] < 15) __builtin_amdgcn_s_sleep(2);
        int base = w * WIN;
        const float* emb = emL[s];
        REFILL(Ae0, Ae1, Ab0, Ab1, emb, 0, base);
        REFILL(Be0, Be1, Bb0, Bb1, emb, 8, base);
        STEPS(Ae0, Ae1, Ab0, Ab1, 0, base);
        REFILL(Ae0, Ae1, Ab0, Ab1, emb, 16, base);
        STEPS(Be0, Be1, Bb0, Bb1, 8, base);
        REFILL(Be0, Be1, Bb0, Bb1, emb, 24, base);
        STEPS(Ae0, Ae1, Ab0, Ab1, 16, base);
        STEPS(Be0, Be1, Bb0, Bb1, 24, base);
        __threadfence_block();               // ring reads done before slot release
        if (lane == 0) {
            atomicExch(&fin[s], 0);          // reset slot, then publish progress
            atomicExch(&cons, w + 1);
        }
    }

    if (cap0 | cap1) {
        float fin_  = blkL[128 + tin - 1];
        float bdtg = decn[(size_t)tg * VV] * L2E;
        out[n] = (res + fin_ + bdtg) * LN2;
    }
}

extern "C" void kernel_launch(void* const* d_in, const int* in_sizes, int n_in,
                              void* d_out, int out_size, void* d_ws, size_t ws_size,
                              hipStream_t hs) {
    const float* enc  = (const float*)d_in[0];
    const float* dec  = (const float*)d_in[1];
    const int*   tgt  = (const int*)d_in[2];
    const int*   ilen = (const int*)d_in[3];
    const int*   tlen = (const int*)d_in[4];
    float* out = (float*)d_out;

    hipLaunchKernelGGL(fused_k, dim3(NB), dim3(1024), 0, hs,
                       enc, dec, tgt, ilen, tlen, out);
}